// Round 1
// baseline (277.890 us; speedup 1.0000x reference)
//
#include <hip/hip_runtime.h>
#include <stdint.h>

#define M_DIM 4096
#define N_DIM 4096
#define K_DIM 4096
#define BM 128
#define BN 128
#define BK 64

typedef __attribute__((ext_vector_type(8))) short short8;    // 8 bf16 = 4 VGPRs
typedef __attribute__((ext_vector_type(4))) float float4v;   // MFMA C/D
typedef __attribute__((ext_vector_type(4))) float f32x4;
typedef __attribute__((ext_vector_type(8))) uint16_t ushort8;

// ---------------- fp32 -> bf16 (RNE) conversion, 8 elems/thread ----------------
__device__ __forceinline__ uint16_t f2bf(float f) {
    uint32_t u = __builtin_bit_cast(uint32_t, f);
    u += 0x7FFFu + ((u >> 16) & 1u);   // round-to-nearest-even
    return (uint16_t)(u >> 16);
}

__global__ __launch_bounds__(256) void cvt_kernel(const float* __restrict__ src,
                                                  uint16_t* __restrict__ dst, int n8) {
    int idx = blockIdx.x * 256 + threadIdx.x;   // handles 8 floats
    if (idx >= n8) return;
    const f32x4* s = (const f32x4*)src;
    f32x4 a = s[idx * 2];
    f32x4 b = s[idx * 2 + 1];
    ushort8 o;
    o[0] = f2bf(a[0]); o[1] = f2bf(a[1]); o[2] = f2bf(a[2]); o[3] = f2bf(a[3]);
    o[4] = f2bf(b[0]); o[5] = f2bf(b[1]); o[6] = f2bf(b[2]); o[7] = f2bf(b[3]);
    *(ushort8*)(dst + (size_t)idx * 8) = o;
}

// ---------------- async global->LDS, 16B per lane ----------------
__device__ __forceinline__ void gload_lds16(const uint16_t* g, uint16_t* l) {
    __builtin_amdgcn_global_load_lds(
        (__attribute__((address_space(1))) void*)(g),
        (__attribute__((address_space(3))) void*)(l),
        16, 0, 0);
}

// ---------------- GEMM: out[m][n] = sum_k A[m][k]*B[n][k], fused scale+gate ----------------
// LDS swizzle: element [row][k] (tile-local, k in 0..63) stored at byte
//   row*128 + ((k/8) ^ (row&7))*16 + (k%8)*2
// Keeps each wave's global_load_lds 1KB destination contiguous; kills the
// 16-lane same-bank-group aliasing of the unswizzled layout.
__global__ __launch_bounds__(256, 2) void trix_gemm(
    const uint16_t* __restrict__ A,      // x   bf16 [4096][4096]
    const uint16_t* __restrict__ B,      // W   bf16 [4096][4096] (O-major, K contig)
    const int* __restrict__ gate,        // [4096][4]
    const float* __restrict__ scales,    // [4096]
    float* __restrict__ out)             // [4096][4096] fp32
{
    __shared__ __align__(16) uint16_t As[BM * BK];   // 16 KB
    __shared__ __align__(16) uint16_t Bs[BN * BK];   // 16 KB

    const int tid  = threadIdx.x;
    const int lane = tid & 63;
    const int wave = tid >> 6;       // 0..3
    const int wm   = wave >> 1;      // 0..1
    const int wn   = wave & 1;       // 0..1
    const int quad = lane >> 4;      // 0..3
    const int ln16 = lane & 15;

    const int m0 = blockIdx.y * BM;
    const int n0 = blockIdx.x * BN;

    // ---- staging addresses: 4 issues each for A and B per K-tile ----
    // issue j covers tile rows [cidx*8, cidx*8+8), cidx = j*4 + wave.
    // lane i: local row = i>>3, row slot chunk = i&7, source chunk = (i&7)^(i>>3)
    const int srow   = lane >> 3;              // 0..7
    const int gchunk = (lane & 7) ^ srow;      // XOR swizzle in GLOBAL address
    const uint16_t* a_src[4];
    const uint16_t* b_src[4];
    uint16_t* a_dst[4];
    uint16_t* b_dst[4];
#pragma unroll
    for (int j = 0; j < 4; ++j) {
        int cidx = j * 4 + wave;
        a_src[j] = A + (size_t)(m0 + cidx * 8 + srow) * K_DIM + gchunk * 8;
        b_src[j] = B + (size_t)(n0 + cidx * 8 + srow) * K_DIM + gchunk * 8;
        a_dst[j] = As + cidx * 512;   // 512 bf16 = 1 KB; HW adds lane*16B
        b_dst[j] = Bs + cidx * 512;
    }

    // ---- fragment read addresses (loop-invariant; single-buffered LDS) ----
    // A-frag (m-tile i, half kk): row = wm*64+i*16+ln16, k = quad*8 + kk*32
    const uint16_t* a_rd[4][2];
    const uint16_t* b_rd[4][2];
#pragma unroll
    for (int i = 0; i < 4; ++i) {
        int arow = wm * 64 + i * 16 + ln16;
        int brow = wn * 64 + i * 16 + ln16;
#pragma unroll
        for (int kk = 0; kk < 2; ++kk) {
            int ch = quad + 4 * kk;
            a_rd[i][kk] = As + arow * 64 + (ch ^ (arow & 7)) * 8;
            b_rd[i][kk] = Bs + brow * 64 + (ch ^ (brow & 7)) * 8;
        }
    }

    float4v acc[4][4];
#pragma unroll
    for (int i = 0; i < 4; ++i)
#pragma unroll
        for (int j = 0; j < 4; ++j)
            acc[i][j] = (float4v){0.f, 0.f, 0.f, 0.f};

    for (int kt = 0; kt < K_DIM; kt += BK) {
        // stage next K-tile (async, drains at the barrier's vmcnt(0))
#pragma unroll
        for (int j = 0; j < 4; ++j) {
            gload_lds16(a_src[j], a_dst[j]);
            gload_lds16(b_src[j], b_dst[j]);
        }
#pragma unroll
        for (int j = 0; j < 4; ++j) { a_src[j] += BK; b_src[j] += BK; }
        __syncthreads();

#pragma unroll
        for (int kk = 0; kk < 2; ++kk) {
            short8 af[4], bf[4];
#pragma unroll
            for (int i = 0; i < 4; ++i) af[i] = *(const short8*)a_rd[i][kk];
#pragma unroll
            for (int i = 0; i < 4; ++i) bf[i] = *(const short8*)b_rd[i][kk];
#pragma unroll
            for (int i = 0; i < 4; ++i)
#pragma unroll
                for (int j = 0; j < 4; ++j)
                    acc[i][j] = __builtin_amdgcn_mfma_f32_16x16x32_bf16(
                        af[i], bf[j], acc[i][j], 0, 0, 0);
        }
        __syncthreads();
    }

    // ---- epilogue: out = acc * scales[n] * gate[m][n>>10] ----
    const int gtile = n0 >> 10;   // block-uniform: 128 | 1024
    float sc[4];
#pragma unroll
    for (int j = 0; j < 4; ++j) sc[j] = scales[n0 + wn * 64 + j * 16 + ln16];

#pragma unroll
    for (int i = 0; i < 4; ++i) {
        int rbase = m0 + wm * 64 + i * 16 + quad * 4;
#pragma unroll
        for (int r = 0; r < 4; ++r) {
            int row = rbase + r;
            float g = (float)gate[row * 4 + gtile];
            float* orow = out + (size_t)row * N_DIM + n0 + wn * 64 + ln16;
#pragma unroll
            for (int j = 0; j < 4; ++j)
                orow[j * 16] = acc[i][j][r] * sc[j] * g;
        }
    }
}

extern "C" void kernel_launch(void* const* d_in, const int* in_sizes, int n_in,
                              void* d_out, int out_size, void* d_ws, size_t ws_size,
                              hipStream_t stream) {
    const float* x      = (const float*)d_in[0];   // [4096][4096]
    const int*   gate   = (const int*)d_in[1];     // [4096][4]
    const float* weight = (const float*)d_in[2];   // [4096][4096]
    const float* scales = (const float*)d_in[3];   // [4096]
    float* out = (float*)d_out;

    uint16_t* xb = (uint16_t*)d_ws;                       // 32 MB bf16 x
    uint16_t* wb = xb + (size_t)M_DIM * K_DIM;            // 32 MB bf16 W

    const int n8 = M_DIM * K_DIM / 8;                     // 2M threads, 8 elems each
    cvt_kernel<<<n8 / 256, 256, 0, stream>>>(x, xb, n8);
    cvt_kernel<<<n8 / 256, 256, 0, stream>>>(weight, wb, n8);

    dim3 grid(N_DIM / BN, M_DIM / BM);                    // 32 x 32 = 1024 blocks
    trix_gemm<<<grid, 256, 0, stream>>>(xb, wb, gate, scales, out);
}

// Round 3
// 277.049 us; speedup vs baseline: 1.0030x; 1.0030x over previous
//
#include <hip/hip_runtime.h>
#include <stdint.h>

#define M_DIM 4096
#define N_DIM 4096
#define K_DIM 4096
#define BM 128
#define BN 128
#define BK 64

typedef __attribute__((ext_vector_type(8))) short short8;    // 8 bf16 = 4 VGPRs
typedef __attribute__((ext_vector_type(4))) float float4v;   // MFMA C/D
typedef __attribute__((ext_vector_type(4))) float f32x4;
typedef __attribute__((ext_vector_type(4))) uint16_t u16x4;

// ---------------- fp32 -> bf16 (RNE) ----------------
__device__ __forceinline__ uint16_t f2bf(float f) {
    uint32_t u = __builtin_bit_cast(uint32_t, f);
    u += 0x7FFFu + ((u >> 16) & 1u);   // round-to-nearest-even
    return (uint16_t)(u >> 16);
}

// One float4 per thread: 16B load + 8B store, perfectly contiguous per wave.
// Converts BOTH x and W in a single dispatch (idx < n4each -> x, else W).
__global__ __launch_bounds__(256) void cvt2_kernel(const float* __restrict__ x,
                                                   const float* __restrict__ w,
                                                   uint16_t* __restrict__ xb,
                                                   uint16_t* __restrict__ wb,
                                                   int n4each) {
    int idx = blockIdx.x * 256 + threadIdx.x;
    const float* src;
    uint16_t* dst;
    int i;
    if (idx < n4each) { src = x; dst = xb; i = idx; }
    else              { src = w; dst = wb; i = idx - n4each; }
    f32x4 a = ((const f32x4*)src)[i];
    u16x4 o;
    o[0] = f2bf(a[0]); o[1] = f2bf(a[1]); o[2] = f2bf(a[2]); o[3] = f2bf(a[3]);
    *(u16x4*)(dst + (size_t)i * 4) = o;
}

// ---------------- async global->LDS, 16B per lane ----------------
__device__ __forceinline__ void gload_lds16(const uint16_t* g, uint16_t* l) {
    __builtin_amdgcn_global_load_lds(
        (__attribute__((address_space(1))) void*)(g),
        (__attribute__((address_space(3))) void*)(l),
        16, 0, 0);
}

// ---------------- GEMM: out[m][n] = sum_k A[m][k]*B[n][k], fused scale+gate ----------------
// LDS swizzle: element [row][k] (tile-local, k in 0..63) stored at byte
//   row*128 + ((k/8) ^ (row&7))*16 + (k%8)*2
// Keeps each wave's global_load_lds 1KB destination contiguous; kills
// same-bank-group aliasing (verified: SQ_LDS_BANK_CONFLICT == 0).
__global__ __launch_bounds__(256, 2) void trix_gemm(
    const uint16_t* __restrict__ A,      // x   bf16 [4096][4096]
    const uint16_t* __restrict__ B,      // W   bf16 [4096][4096] (O-major, K contig)
    const int* __restrict__ gate,        // [4096][4]
    const float* __restrict__ scales,    // [4096]
    float* __restrict__ out)             // [4096][4096] fp32
{
    __shared__ __align__(16) uint16_t As[BM * BK];   // 16 KB
    __shared__ __align__(16) uint16_t Bs[BN * BK];   // 16 KB

    const int tid  = threadIdx.x;
    const int lane = tid & 63;
    const int wave = tid >> 6;       // 0..3
    const int wm   = wave >> 1;      // 0..1
    const int wn   = wave & 1;       // 0..1
    const int quad = lane >> 4;      // 0..3
    const int ln16 = lane & 15;

    const int m0 = blockIdx.y * BM;
    const int n0 = blockIdx.x * BN;

    // ---- staging addresses: 4 issues each for A and B per K-tile ----
    const int srow   = lane >> 3;              // 0..7
    const int gchunk = (lane & 7) ^ srow;      // XOR swizzle in GLOBAL address
    const uint16_t* a_src[4];
    const uint16_t* b_src[4];
    uint16_t* a_dst[4];
    uint16_t* b_dst[4];
#pragma unroll
    for (int j = 0; j < 4; ++j) {
        int cidx = j * 4 + wave;
        a_src[j] = A + (size_t)(m0 + cidx * 8 + srow) * K_DIM + gchunk * 8;
        b_src[j] = B + (size_t)(n0 + cidx * 8 + srow) * K_DIM + gchunk * 8;
        a_dst[j] = As + cidx * 512;   // 512 bf16 = 1 KB; HW adds lane*16B
        b_dst[j] = Bs + cidx * 512;
    }

    // ---- fragment read addresses (loop-invariant; single-buffered LDS) ----
    const uint16_t* a_rd[4][2];
    const uint16_t* b_rd[4][2];
#pragma unroll
    for (int i = 0; i < 4; ++i) {
        int arow = wm * 64 + i * 16 + ln16;
        int brow = wn * 64 + i * 16 + ln16;
#pragma unroll
        for (int kk = 0; kk < 2; ++kk) {
            int ch = quad + 4 * kk;
            a_rd[i][kk] = As + arow * 64 + (ch ^ (arow & 7)) * 8;
            b_rd[i][kk] = Bs + brow * 64 + (ch ^ (brow & 7)) * 8;
        }
    }

    float4v acc[4][4];
#pragma unroll
    for (int i = 0; i < 4; ++i)
#pragma unroll
        for (int j = 0; j < 4; ++j)
            acc[i][j] = (float4v){0.f, 0.f, 0.f, 0.f};

    for (int kt = 0; kt < K_DIM; kt += BK) {
#pragma unroll
        for (int j = 0; j < 4; ++j) {
            gload_lds16(a_src[j], a_dst[j]);
            gload_lds16(b_src[j], b_dst[j]);
        }
#pragma unroll
        for (int j = 0; j < 4; ++j) { a_src[j] += BK; b_src[j] += BK; }
        __syncthreads();

#pragma unroll
        for (int kk = 0; kk < 2; ++kk) {
            short8 af[4], bf[4];
#pragma unroll
            for (int i = 0; i < 4; ++i) af[i] = *(const short8*)a_rd[i][kk];
#pragma unroll
            for (int i = 0; i < 4; ++i) bf[i] = *(const short8*)b_rd[i][kk];
#pragma unroll
            for (int i = 0; i < 4; ++i)
#pragma unroll
                for (int j = 0; j < 4; ++j)
                    acc[i][j] = __builtin_amdgcn_mfma_f32_16x16x32_bf16(
                        af[i], bf[j], acc[i][j], 0, 0, 0);
        }
        __syncthreads();
    }

    // ---- epilogue: out = acc * scales[n] * gate[m][n>>10] ----
    const int gtile = n0 >> 10;   // block-uniform: 128 | 1024
    float sc[4];
#pragma unroll
    for (int j = 0; j < 4; ++j) sc[j] = scales[n0 + wn * 64 + j * 16 + ln16];

#pragma unroll
    for (int i = 0; i < 4; ++i) {
        int rbase = m0 + wm * 64 + i * 16 + quad * 4;
#pragma unroll
        for (int r = 0; r < 4; ++r) {
            int row = rbase + r;
            float g = (float)gate[row * 4 + gtile];
            float* orow = out + (size_t)row * N_DIM + n0 + wn * 64 + ln16;
#pragma unroll
            for (int j = 0; j < 4; ++j)
                orow[j * 16] = acc[i][j][r] * sc[j] * g;
        }
    }
}

extern "C" void kernel_launch(void* const* d_in, const int* in_sizes, int n_in,
                              void* d_out, int out_size, void* d_ws, size_t ws_size,
                              hipStream_t stream) {
    const float* x      = (const float*)d_in[0];   // [4096][4096]
    const int*   gate   = (const int*)d_in[1];     // [4096][4]
    const float* weight = (const float*)d_in[2];   // [4096][4096]
    const float* scales = (const float*)d_in[3];   // [4096]
    float* out = (float*)d_out;

    uint16_t* xb = (uint16_t*)d_ws;                       // 32 MB bf16 x
    uint16_t* wb = xb + (size_t)M_DIM * K_DIM;            // 32 MB bf16 W

    const int n4each = M_DIM * K_DIM / 4;                 // 4M float4 per array
    const int total_threads = 2 * n4each;                 // both arrays, one dispatch
    cvt2_kernel<<<total_threads / 256, 256, 0, stream>>>(x, weight, xb, wb, n4each);

    dim3 grid(N_DIM / BN, M_DIM / BM);                    // 32 x 32 = 1024 blocks
    trix_gemm<<<grid, 256, 0, stream>>>(xb, wb, gate, scales, out);
}

// Round 4
// 230.397 us; speedup vs baseline: 1.2061x; 1.2025x over previous
//
#include <hip/hip_runtime.h>
#include <stdint.h>

#define M_DIM 4096
#define N_DIM 4096
#define K_DIM 4096
#define BM 128
#define BN 128
#define BKB 128   // K-bytes (= i8 elems) per tile

typedef __attribute__((ext_vector_type(4))) int     int4v;  // 16 i8 = 4 VGPRs, or 4 i32 acc
typedef __attribute__((ext_vector_type(4))) float   f32x4;
typedef __attribute__((ext_vector_type(8))) uint8_t u8x8;

#define XSCALE (127.0f / 4.25f)
#define XDEQ   (4.25f / 127.0f)

// ---------------- fp32 -> i8 quantizers ----------------
__device__ __forceinline__ int8_t q8(float v) {
    float c = fminf(fmaxf(v * XSCALE, -127.0f), 127.0f);
    return (int8_t)(int)__builtin_rintf(c);
}
__device__ __forceinline__ int8_t s8(float v) {           // exact ternary sign
    return (int8_t)((v > 0.0f) - (v < 0.0f));
}

// One dispatch converts both x (quantize) and W (sign). 8 elems/thread:
// 32B contiguous load + 8B contiguous store per lane.
__global__ __launch_bounds__(256) void cvt_i8_kernel(const float* __restrict__ x,
                                                     const float* __restrict__ w,
                                                     int8_t* __restrict__ xq,
                                                     int8_t* __restrict__ wq,
                                                     int n8each) {
    int idx = blockIdx.x * 256 + threadIdx.x;
    u8x8 o;
    if (idx < n8each) {
        const f32x4* s = (const f32x4*)x;
        f32x4 a = s[idx * 2], b = s[idx * 2 + 1];
        o[0] = (uint8_t)q8(a[0]); o[1] = (uint8_t)q8(a[1]);
        o[2] = (uint8_t)q8(a[2]); o[3] = (uint8_t)q8(a[3]);
        o[4] = (uint8_t)q8(b[0]); o[5] = (uint8_t)q8(b[1]);
        o[6] = (uint8_t)q8(b[2]); o[7] = (uint8_t)q8(b[3]);
        *(u8x8*)(xq + (size_t)idx * 8) = o;
    } else {
        int i = idx - n8each;
        const f32x4* s = (const f32x4*)w;
        f32x4 a = s[i * 2], b = s[i * 2 + 1];
        o[0] = (uint8_t)s8(a[0]); o[1] = (uint8_t)s8(a[1]);
        o[2] = (uint8_t)s8(a[2]); o[3] = (uint8_t)s8(a[3]);
        o[4] = (uint8_t)s8(b[0]); o[5] = (uint8_t)s8(b[1]);
        o[6] = (uint8_t)s8(b[2]); o[7] = (uint8_t)s8(b[3]);
        *(u8x8*)(wq + (size_t)i * 8) = o;
    }
}

// ---------------- async global->LDS, 16B per lane ----------------
__device__ __forceinline__ void gload_lds16(const int8_t* g, int8_t* l) {
    __builtin_amdgcn_global_load_lds(
        (__attribute__((address_space(1))) void*)(g),
        (__attribute__((address_space(3))) void*)(l),
        16, 0, 0);
}

// ---------------- i8 GEMM: out[m][n] = (sum_k xq[m][k]*wq[n][k]) * dq * scales[n] * gate ----
// Byte-identical LDS geometry to the verified bf16 kernel (128 B/row, 8x16B
// chunks, XOR swizzle chunk^(row&7)) -> conflict-free staging + b128 reads.
__global__ __launch_bounds__(256, 2) void trix_gemm(
    const int8_t* __restrict__ A,        // xq i8 [4096][4096]
    const int8_t* __restrict__ B,        // wq i8 [4096][4096] (O-major, K contig)
    const int* __restrict__ gate,        // [4096][4]
    const float* __restrict__ scales,    // [4096]
    float* __restrict__ out)             // [4096][4096] fp32
{
    __shared__ __align__(16) int8_t As[BM * BKB];   // 16 KB
    __shared__ __align__(16) int8_t Bs[BN * BKB];   // 16 KB

    const int tid  = threadIdx.x;
    const int lane = tid & 63;
    const int wave = tid >> 6;       // 0..3
    const int wm   = wave >> 1;      // 0..1
    const int wn   = wave & 1;       // 0..1
    const int quad = lane >> 4;      // 0..3
    const int ln16 = lane & 15;

    const int m0 = blockIdx.y * BM;
    const int n0 = blockIdx.x * BN;

    // ---- staging: 4 issues each for A and B per K-tile (1 KB per issue) ----
    const int srow   = lane >> 3;              // 0..7
    const int gchunk = (lane & 7) ^ srow;      // XOR swizzle in GLOBAL address
    const int8_t* a_src[4];
    const int8_t* b_src[4];
    int8_t* a_dst[4];
    int8_t* b_dst[4];
#pragma unroll
    for (int j = 0; j < 4; ++j) {
        int cidx = j * 4 + wave;
        a_src[j] = A + (size_t)(m0 + cidx * 8 + srow) * K_DIM + gchunk * 16;
        b_src[j] = B + (size_t)(n0 + cidx * 8 + srow) * K_DIM + gchunk * 16;
        a_dst[j] = As + cidx * 1024;   // 8 rows x 128 B; HW adds lane*16B
        b_dst[j] = Bs + cidx * 1024;
    }

    // ---- fragment read addresses: lane reads 16 i8 at row, k = quad*16 + kk*64 ----
    const int8_t* a_rd[4][2];
    const int8_t* b_rd[4][2];
#pragma unroll
    for (int i = 0; i < 4; ++i) {
        int arow = wm * 64 + i * 16 + ln16;
        int brow = wn * 64 + i * 16 + ln16;
#pragma unroll
        for (int kk = 0; kk < 2; ++kk) {
            int ch = quad + 4 * kk;
            a_rd[i][kk] = As + arow * 128 + ((ch ^ (arow & 7)) * 16);
            b_rd[i][kk] = Bs + brow * 128 + ((ch ^ (brow & 7)) * 16);
        }
    }

    int4v acc[4][4];
#pragma unroll
    for (int i = 0; i < 4; ++i)
#pragma unroll
        for (int j = 0; j < 4; ++j)
            acc[i][j] = (int4v){0, 0, 0, 0};

    for (int kt = 0; kt < K_DIM; kt += BKB) {   // 32 tiles
#pragma unroll
        for (int j = 0; j < 4; ++j) {
            gload_lds16(a_src[j], a_dst[j]);
            gload_lds16(b_src[j], b_dst[j]);
        }
#pragma unroll
        for (int j = 0; j < 4; ++j) { a_src[j] += BKB; b_src[j] += BKB; }
        __syncthreads();

#pragma unroll
        for (int kk = 0; kk < 2; ++kk) {
            int4v af[4], bf[4];
#pragma unroll
            for (int i = 0; i < 4; ++i) af[i] = *(const int4v*)a_rd[i][kk];
#pragma unroll
            for (int i = 0; i < 4; ++i) bf[i] = *(const int4v*)b_rd[i][kk];
#pragma unroll
            for (int i = 0; i < 4; ++i)
#pragma unroll
                for (int j = 0; j < 4; ++j)
                    acc[i][j] = __builtin_amdgcn_mfma_i32_16x16x64_i8(
                        af[i], bf[j], acc[i][j], 0, 0, 0);
        }
        __syncthreads();
    }

    // ---- epilogue: out = acc_i32 * (4.25/127) * scales[n] * gate[m][n>>10] ----
    const int gtile = n0 >> 10;   // block-uniform: 128 | 1024
    float sc[4];
#pragma unroll
    for (int j = 0; j < 4; ++j) sc[j] = scales[n0 + wn * 64 + j * 16 + ln16] * XDEQ;

#pragma unroll
    for (int i = 0; i < 4; ++i) {
        int rbase = m0 + wm * 64 + i * 16 + quad * 4;
#pragma unroll
        for (int r = 0; r < 4; ++r) {
            int row = rbase + r;
            float g = (float)gate[row * 4 + gtile];
            float* orow = out + (size_t)row * N_DIM + n0 + wn * 64 + ln16;
#pragma unroll
            for (int j = 0; j < 4; ++j)
                orow[j * 16] = (float)acc[i][j][r] * sc[j] * g;
        }
    }
}

extern "C" void kernel_launch(void* const* d_in, const int* in_sizes, int n_in,
                              void* d_out, int out_size, void* d_ws, size_t ws_size,
                              hipStream_t stream) {
    const float* x      = (const float*)d_in[0];   // [4096][4096]
    const int*   gate   = (const int*)d_in[1];     // [4096][4]
    const float* weight = (const float*)d_in[2];   // [4096][4096]
    const float* scales = (const float*)d_in[3];   // [4096]
    float* out = (float*)d_out;

    int8_t* xq = (int8_t*)d_ws;                           // 16 MB i8 x
    int8_t* wq = xq + (size_t)M_DIM * K_DIM;              // 16 MB i8 W

    const int n8each = M_DIM * K_DIM / 8;                 // 2M threads per array
    const int total_threads = 2 * n8each;
    cvt_i8_kernel<<<total_threads / 256, 256, 0, stream>>>(x, weight, xq, wq, n8each);

    dim3 grid(N_DIM / BN, M_DIM / BM);                    // 32 x 32 = 1024 blocks
    trix_gemm<<<grid, 256, 0, stream>>>(xq, wq, gate, scales, out);
}